// Round 9
// baseline (43.825 us; speedup 1.0000x reference)
//
#include <hip/hip_runtime.h>

// Problem: x:[B=64,S=2048,K=256] f32, W:[K=256,D=512] f32
// out[b,d] = mean_s(x) @ W  -> [64,512] f32
// Single kernel, 1280 blocks: 1024 producers stream-reduce x (128 MiB,
// HBM-bound) and atomicAdd per-k sums into acc[b][k] (atomics land at the
// device-coherent point -> no fences/wbl2 needed); each bumps cnt[b] after
// vmcnt(0)+barrier. 256 waiter blocks (4 per b) poll cnt[b]==16, then read
// acc via agent-scope atomic loads and do the 128-col W dot -> overlapped
// with the streaming tail. No second launch, no drain gap.

typedef float f32x4 __attribute__((ext_vector_type(4)));

#define BB 64
#define SS 2048
#define KK 256
#define DD 512
#define CHUNKS 16
#define RPC (SS / CHUNKS)    // 128 rows per chunk
#define NPROD (BB * CHUNKS)  // 1024 producer blocks
#define NFIN (BB * 4)        // 256 finisher blocks
#define NXCD 8

__global__ __launch_bounds__(256) void fused_kernel(const float* __restrict__ x,
                                                    const float* __restrict__ w,
                                                    float* __restrict__ out,
                                                    float* __restrict__ acc,
                                                    unsigned int* __restrict__ cnt) {
    const int t = threadIdx.x;

    if (blockIdx.x < NPROD) {
        // ---- Producer: stream 128 rows, reduce to K-vector, atomicAdd ----
        const int virt = (blockIdx.x & (NXCD - 1)) * (NPROD / NXCD) + (blockIdx.x >> 3);
        const int b  = virt >> 4;        // / CHUNKS
        const int c  = virt & 15;        // % CHUNKS
        const int tx = t & 63;           // f32x4 lane across K (64*4 = 256)
        const int ty = t >> 6;           // 0..3

        const f32x4* xp = (const f32x4*)(x + ((size_t)b * SS + (size_t)c * RPC) * KK) + tx;

        f32x4 a = {0.f, 0.f, 0.f, 0.f};
        #pragma unroll
        for (int i = 0; i < RPC / 4; ++i)
            a += xp[(size_t)(i * 4 + ty) * (KK / 4)];

        __shared__ float sm[4][KK];
        *(f32x4*)&sm[ty][tx * 4] = a;
        __syncthreads();

        const float v = (sm[0][t] + sm[1][t]) + (sm[2][t] + sm[3][t]);
        atomicAdd(&acc[(size_t)b * KK + t], v);          // coherent point, no fence
        asm volatile("s_waitcnt vmcnt(0)" ::: "memory"); // my add is globally done
        __syncthreads();                                 // whole block's adds done
        if (t == 0) atomicAdd(&cnt[b], 1u);
    } else {
        // ---- Finisher: 4 blocks per b, each 128 output cols ----
        const int wblk = blockIdx.x - NPROD;
        const int b  = wblk >> 2;
        const int dq = wblk & 3;

        if (t == 0) {
            while (__hip_atomic_load(&cnt[b], __ATOMIC_RELAXED, __HIP_MEMORY_SCOPE_AGENT)
                   < (unsigned)CHUNKS)
                __builtin_amdgcn_s_sleep(8);             // ~0.2 us per poll
        }
        __syncthreads();

        __shared__ float xm[KK];
        xm[t] = __hip_atomic_load(&acc[(size_t)b * KK + t], __ATOMIC_RELAXED,
                                  __HIP_MEMORY_SCOPE_AGENT) * (1.0f / SS);
        __syncthreads();

        const int col4 = dq * 32 + (t & 31); // f32x4 column in [0, 128)
        const int kg   = t >> 5;             // k-group 0..7, 32 k's each
        const f32x4* w4 = (const f32x4*)w;

        f32x4 o = {0.f, 0.f, 0.f, 0.f};
        #pragma unroll
        for (int kk = 0; kk < 32; ++kk) {
            const int k = kg * 32 + kk;
            o += xm[k] * w4[(size_t)k * (DD / 4) + col4];
        }

        __shared__ f32x4 red[8][32];
        if (kg) red[kg][t & 31] = o;
        __syncthreads();
        if (kg == 0) {
            #pragma unroll
            for (int g = 1; g < 8; ++g) o += red[g][t];
            ((f32x4*)out)[(size_t)b * (DD / 4) + col4] = o;
        }
    }
}

extern "C" void kernel_launch(void* const* d_in, const int* in_sizes, int n_in,
                              void* d_out, int out_size, void* d_ws, size_t ws_size,
                              hipStream_t stream) {
    const float* x = (const float*)d_in[0];
    const float* w = (const float*)d_in[1];
    float* out = (float*)d_out;
    float* acc = (float*)d_ws;                               // BB*KK floats
    unsigned int* cnt = (unsigned int*)(acc + BB * KK);      // BB counters

    hipMemsetAsync(d_ws, 0, (BB * KK + BB) * sizeof(float), stream);
    fused_kernel<<<NPROD + NFIN, 256, 0, stream>>>(x, w, out, acc, cnt);
}

// Round 10
// 28.453 us; speedup vs baseline: 1.5403x; 1.5403x over previous
//
#include <hip/hip_runtime.h>

// Problem: x:[B=64,S=2048,K=256] f32, W:[K=256,D=512] f32
// out[b,d] = mean_s(x) @ W  -> [64,512] f32
// Stage A: seq-reduce x into [B,16,K] partials (128 MiB streaming read,
// HBM-bound). XCD-contiguous block swizzle: 1024 blocks / 8 XCDs -> each XCD
// streams one contiguous ~16.8 MB partition of x (DRAM/fabric locality)
// instead of 128 KB round-robin fragments. Fully-resident grid (4 blk/CU).
// Stage B: 256 blocks, split-k 8, f32x4 W loads (W L2-hot).
// NOTE: fusion attempts (r4 fence-elect, r9 atomic+waiters) both regressed
// badly — inter-block producer/consumer costs more than the ~3.5us tail.

typedef float f32x4 __attribute__((ext_vector_type(4)));

#define BB 64
#define SS 2048
#define KK 256
#define DD 512
#define CHUNKS 16
#define RPC (SS / CHUNKS)   // 128 rows per chunk
#define NBLK (BB * CHUNKS)  // 1024
#define NXCD 8

// Stage A: one (virtual) block per (b, chunk). 256 threads = 64 f32x4 lanes
// across K x 4 rows in s; 32 row-iterations per thread.
__global__ __launch_bounds__(256) void partial_sum_kernel(const float* __restrict__ x,
                                                          float* __restrict__ part) {
    // XCD-contiguous swizzle: hw blocks round-robin over 8 XCDs; give XCD i
    // the contiguous virtual range [i*128, (i+1)*128). NBLK % NXCD == 0.
    const int virt = (blockIdx.x & (NXCD - 1)) * (NBLK / NXCD) + (blockIdx.x >> 3);
    const int b  = virt >> 4;            // / CHUNKS
    const int c  = virt & 15;            // % CHUNKS
    const int t  = threadIdx.x;
    const int tx = t & 63;               // f32x4 index across K (64*4 = 256)
    const int ty = t >> 6;               // 0..3

    const f32x4* xp = (const f32x4*)(x + ((size_t)b * SS + (size_t)c * RPC) * KK) + tx;

    f32x4 acc = {0.f, 0.f, 0.f, 0.f};
    #pragma unroll
    for (int i = 0; i < RPC / 4; ++i)
        acc += xp[(size_t)(i * 4 + ty) * (KK / 4)];

    __shared__ f32x4 smem[4][64];
    smem[ty][tx] = acc;
    __syncthreads();

    if (ty == 0) {
        f32x4 r = (smem[0][tx] + smem[1][tx]) + (smem[2][tx] + smem[3][tx]);
        ((f32x4*)(part + ((size_t)b * CHUNKS + c) * KK))[tx] = r;
    }
}

// Stage B: 4 blocks per b. Block (b,dq): 128 output cols (32 f32x4),
// split-k 8-way across thread groups, LDS reduce, store.
__global__ __launch_bounds__(256) void finish_kernel(const float* __restrict__ part,
                                                     const float* __restrict__ w,
                                                     float* __restrict__ out) {
    const int b  = blockIdx.x >> 2;
    const int dq = blockIdx.x & 3;
    const int t  = threadIdx.x;          // 0..255

    __shared__ float xm[KK];
    {
        float s = 0.f;
        const float* pp = part + (size_t)b * CHUNKS * KK + t;
        #pragma unroll
        for (int c = 0; c < CHUNKS; ++c) s += pp[c * KK];       // fixed order
        xm[t] = s * (1.0f / SS);
    }
    __syncthreads();

    const int col4 = dq * 32 + (t & 31); // f32x4 column in [0, 128)
    const int kg   = t >> 5;             // k-group 0..7, 32 k's each
    const f32x4* w4 = (const f32x4*)w;

    f32x4 acc = {0.f, 0.f, 0.f, 0.f};
    #pragma unroll
    for (int kk = 0; kk < 32; ++kk) {
        const int k = kg * 32 + kk;
        acc += xm[k] * w4[(size_t)k * (DD / 4) + col4];         // 16B coalesced
    }

    __shared__ f32x4 red[8][32];
    if (kg) red[kg][t & 31] = acc;
    __syncthreads();
    if (kg == 0) {
        #pragma unroll
        for (int g = 1; g < 8; ++g) acc += red[g][t];
        ((f32x4*)out)[(size_t)b * (DD / 4) + col4] = acc;
    }
}

extern "C" void kernel_launch(void* const* d_in, const int* in_sizes, int n_in,
                              void* d_out, int out_size, void* d_ws, size_t ws_size,
                              hipStream_t stream) {
    const float* x = (const float*)d_in[0];
    const float* w = (const float*)d_in[1];
    float* out  = (float*)d_out;
    float* part = (float*)d_ws;   // B*CHUNKS*K floats = 1 MiB

    partial_sum_kernel<<<NBLK, 256, 0, stream>>>(x, part);
    finish_kernel<<<BB * 4, 256, 0, stream>>>(part, w, out);
}